// Round 15
// baseline (358.592 us; speedup 1.0000x reference)
//
#include <hip/hip_runtime.h>
#include <hip/hip_bf16.h>

#define EPSF 1e-5f
#define IOU_THRF 0.9f
#define NBOX 9216
#define NWORDS 144   // 9216/64
#define CAND_CAP 4096
#define FIRE_CAP 1024
#define CD_TILES 684   // 512-row x 128-col upper-tri tiles: sum(72-4*rg)

// ---------------- depthwise 3x3 conv, C=256, 32x32, pad 1 ----------------
__global__ __launch_bounds__(256) void dw_conv(const float* __restrict__ x,
                                               const float* __restrict__ w,
                                               float* __restrict__ h0) {
    int idx = blockIdx.x * 256 + threadIdx.x;   // 262144 threads
    int c = idx >> 10, p = idx & 1023;
    int yy = p >> 5, xx = p & 31;
    const float* xi = x + (c << 10);
    const float* wc = w + c * 9;
    float acc = 0.f;
    #pragma unroll
    for (int dy = -1; dy <= 1; ++dy) {
        int y2 = yy + dy;
        if ((unsigned)y2 >= 32u) continue;
        #pragma unroll
        for (int dx = -1; dx <= 1; ++dx) {
            int x2 = xx + dx;
            if ((unsigned)x2 >= 32u) continue;
            acc += wc[(dy + 1) * 3 + (dx + 1)] * xi[y2 * 32 + x2];
        }
    }
    h0[idx] = acc;
}

// ---------------- pointwise 256x256 GEMM + BN1 + leaky relu ----------------
__global__ __launch_bounds__(256) void pw_conv(const float* __restrict__ h0,
                                               const float* __restrict__ w,
                                               const float* __restrict__ g,
                                               const float* __restrict__ b,
                                               const float* __restrict__ mu,
                                               const float* __restrict__ var,
                                               float* __restrict__ h1) {
    int p = blockIdx.x * 256 + threadIdx.x;
    int o0 = blockIdx.y * 4;
    float acc0 = 0.f, acc1 = 0.f, acc2 = 0.f, acc3 = 0.f;
    for (int c = 0; c < 256; ++c) {
        float hv = h0[(c << 10) + p];
        acc0 += w[(o0 + 0) * 256 + c] * hv;
        acc1 += w[(o0 + 1) * 256 + c] * hv;
        acc2 += w[(o0 + 2) * 256 + c] * hv;
        acc3 += w[(o0 + 3) * 256 + c] * hv;
    }
    float accs[4] = {acc0, acc1, acc2, acc3};
    #pragma unroll
    for (int k = 0; k < 4; ++k) {
        int o = o0 + k;
        float inv = 1.0f / sqrtf(var[o] + EPSF);
        float v = (accs[k] - mu[o]) * (inv * g[o]) + b[o];
        v = (v >= 0.f) ? v : 0.01f * v;
        h1[(o << 10) + p] = v;
    }
}

// ---------------- heads: anc (36 ch) + obj (9 ch) GEMV + BN + decode ----------------
__global__ __launch_bounds__(256) void heads(const float* __restrict__ h1,
                                             const float* __restrict__ anc_w,
                                             const float* __restrict__ ag,
                                             const float* __restrict__ ab,
                                             const float* __restrict__ am,
                                             const float* __restrict__ av,
                                             const float* __restrict__ obj_w,
                                             const float* __restrict__ og,
                                             const float* __restrict__ ob,
                                             const float* __restrict__ om,
                                             const float* __restrict__ ov,
                                             const float* __restrict__ anchors,
                                             float* __restrict__ boxes,
                                             float* __restrict__ scores) {
    int p = blockIdx.x * 256 + threadIdx.x;
    int o = blockIdx.y;
    const float* wrow = (o < 36) ? (anc_w + o * 256) : (obj_w + (o - 36) * 256);
    float acc = 0.f;
    for (int c = 0; c < 256; ++c) acc += wrow[c] * h1[(c << 10) + p];
    if (o < 36) {
        float inv = 1.0f / sqrtf(av[o] + EPSF);
        float v = (acc - am[o]) * (inv * ag[o]) + ab[o];
        v = fminf(fmaxf(v, 0.f), 6.f);           // clip 0..6
        int a = o >> 2, k = o & 3;
        float anch = anchors[a * 4 + k];
        float val = (k < 2) ? (v + anch) : (expf(v) * anch);
        boxes[(size_t)(a * 1024 + p) * 4 + k] = val;
    } else {
        int a = o - 36;
        float inv = 1.0f / sqrtf(ov[a] + EPSF);
        float v = (acc - om[a]) * (inv * og[a]) + ob[a];
        scores[a * 1024 + p] = 1.0f / (1.0f + expf(-v));
    }
}

// ---------------- rank = stable-descending-argsort position, O(N^2) count ----------------
__global__ __launch_bounds__(256) void rank_partial(const float* __restrict__ scores,
                                                    unsigned* __restrict__ rank) {
    __shared__ float4 sm[144];
    int mbase = blockIdx.y * 576;
    for (int t = threadIdx.x; t < 144; t += 256)
        sm[t] = ((const float4*)(scores + mbase))[t];
    __syncthreads();
    int n = blockIdx.x * 256 + threadIdx.x;
    float s = scores[n];
    unsigned cnt = 0;
    for (int q = 0; q < 144; ++q) {
        float4 v = sm[q];
        int m = mbase + q * 4;
        cnt += (v.x > s) || (v.x == s && (m + 0) < n);
        cnt += (v.y > s) || (v.y == s && (m + 1) < n);
        cnt += (v.z > s) || (v.z == s && (m + 2) < n);
        cnt += (v.w > s) || (v.w == s && (m + 3) < n);
    }
    atomicAdd(&rank[n], cnt);
}

// ---------------- scatter into sorted order ----------------
__global__ __launch_bounds__(256) void scatter_sorted(const float* __restrict__ boxes,
                                                      const unsigned* __restrict__ rank,
                                                      int* __restrict__ order,
                                                      float* __restrict__ sboxes,
                                                      float* __restrict__ sareas) {
    int n = blockIdx.x * 256 + threadIdx.x;
    unsigned r = rank[n];
    order[r] = n;
    float4 bx = ((const float4*)boxes)[n];
    ((float4*)sboxes)[r] = bx;
    sareas[r] = (bx.z - bx.x) * (bx.w - bx.y);
}

// ---------------- candidate detection, sign-guarded prescreen ----------------
// 684 tiles of 512 rows x 128 cols (2 rows/thread). Hit requires denom>=0
// (denom<0 => iou<=0; denom==0 & inter>0 => +inf hit). Screen per pair:
// C = (inter > 0.85*denom) && (denom >= 0)  — conservative (0.85 vs 0.9 gap
// >> rounding), false for ALL negative-denom pairs (negative areas common).
// Rows with C (iou ~> 0.85, rare) redo with the exact reference division.
__global__ __launch_bounds__(256) void cand_detect(const float* __restrict__ sboxes,
                                                   const float* __restrict__ sareas,
                                                   unsigned long long* __restrict__ rnz64) {
    __shared__ float4 B4[128];
    __shared__ float CARs[128];
    int rem = blockIdx.x, rg = 0;
    while (rem >= 72 - 4 * rg) { rem -= 72 - 4 * rg; ++rg; }
    int sc = 4 * rg + rem;
    int tid = threadIdx.x;
    if (tid < 128) {
        int j = sc * 128 + tid;
        B4[tid] = ((const float4*)sboxes)[j];
        CARs[tid] = sareas[j];
    }
    __syncthreads();
    int i0 = rg * 512 + tid, i1 = i0 + 256;
    float4 bb0 = ((const float4*)sboxes)[i0];
    float4 bb1 = ((const float4*)sboxes)[i1];
    float ar0 = sareas[i0], ar1 = sareas[i1];
    bool p0 = false, p1 = false;

    if (sc >= 4 * rg + 4) {
        // all j > i guaranteed
        #pragma unroll 4
        for (int idx = 0; idx < 128; ++idx) {
            float4 cb = B4[idx]; float aa = CARs[idx];
            float ix0 = fminf(bb0.z, cb.z) - fmaxf(bb0.x, cb.x);
            float iy0 = fminf(bb0.w, cb.w) - fmaxf(bb0.y, cb.y);
            float t0 = fmaxf(ix0, 0.f) * fmaxf(iy0, 0.f);
            float d0 = ar0 + aa - t0;
            p0 |= (t0 > 0.85f * d0) && (d0 >= 0.f);
            float ix1 = fminf(bb1.z, cb.z) - fmaxf(bb1.x, cb.x);
            float iy1 = fminf(bb1.w, cb.w) - fmaxf(bb1.y, cb.y);
            float t1 = fmaxf(ix1, 0.f) * fmaxf(iy1, 0.f);
            float d1 = ar1 + aa - t1;
            p1 |= (t1 > 0.85f * d1) && (d1 >= 0.f);
        }
    } else {
        #pragma unroll 4
        for (int idx = 0; idx < 128; ++idx) {
            int j = sc * 128 + idx;
            float4 cb = B4[idx]; float aa = CARs[idx];
            float ix0 = fminf(bb0.z, cb.z) - fmaxf(bb0.x, cb.x);
            float iy0 = fminf(bb0.w, cb.w) - fmaxf(bb0.y, cb.y);
            float t0 = fmaxf(ix0, 0.f) * fmaxf(iy0, 0.f);
            float d0 = ar0 + aa - t0;
            p0 |= (j > i0) && (t0 > 0.85f * d0) && (d0 >= 0.f);
            float ix1 = fminf(bb1.z, cb.z) - fmaxf(bb1.x, cb.x);
            float iy1 = fminf(bb1.w, cb.w) - fmaxf(bb1.y, cb.y);
            float t1 = fmaxf(ix1, 0.f) * fmaxf(iy1, 0.f);
            float d1 = ar1 + aa - t1;
            p1 |= (j > i1) && (t1 > 0.85f * d1) && (d1 >= 0.f);
        }
    }
    bool cand0 = false, cand1 = false;
    if (p0) {   // exact redo with reference formula (iou~>0.85 rows only)
        for (int idx = 0; idx < 128; ++idx) {
            float4 cb = B4[idx];
            float ix = fminf(bb0.z, cb.z) - fmaxf(bb0.x, cb.x);
            float iy = fminf(bb0.w, cb.w) - fmaxf(bb0.y, cb.y);
            float inter = fmaxf(ix, 0.f) * fmaxf(iy, 0.f);
            float denom = ar0 + CARs[idx] - inter;
            int j = sc * 128 + idx;
            if (j > i0 && inter / denom > IOU_THRF) cand0 = true;
        }
    }
    if (p1) {
        for (int idx = 0; idx < 128; ++idx) {
            float4 cb = B4[idx];
            float ix = fminf(bb1.z, cb.z) - fmaxf(bb1.x, cb.x);
            float iy = fminf(bb1.w, cb.w) - fmaxf(bb1.y, cb.y);
            float inter = fmaxf(ix, 0.f) * fmaxf(iy, 0.f);
            float denom = ar1 + CARs[idx] - inter;
            int j = sc * 128 + idx;
            if (j > i1 && inter / denom > IOU_THRF) cand1 = true;
        }
    }
    unsigned long long bal = __ballot(cand0);
    if ((tid & 63) == 0) atomicOr(&rnz64[rg * 8 + (tid >> 6)], bal);
    bal = __ballot(cand1);
    if ((tid & 63) == 0) atomicOr(&rnz64[rg * 8 + 4 + (tid >> 6)], bal);
}

__device__ inline unsigned long long rdl64(unsigned long long v, int l) {
    unsigned lo = (unsigned)__builtin_amdgcn_readlane((int)(unsigned)(v & 0xffffffffull), l);
    unsigned hi = (unsigned)__builtin_amdgcn_readlane((int)(unsigned)(v >> 32), l);
    return ((unsigned long long)hi << 32) | lo;
}

// ---------------- compact candidates, PARALLEL (36 blocks) ----------------
__global__ __launch_bounds__(256) void compact_cand2(const unsigned long long* __restrict__ rnz64,
                                                     const float* __restrict__ sboxes,
                                                     const float* __restrict__ sareas,
                                                     int* __restrict__ cidx,
                                                     float4* __restrict__ cboxes,
                                                     float* __restrict__ carea,
                                                     int* __restrict__ knum) {
    __shared__ int incl[256];
    int tid = threadIdx.x;
    int myc = (tid < NWORDS) ? (int)__popcll(rnz64[tid]) : 0;
    incl[tid] = myc;
    __syncthreads();
    #pragma unroll
    for (int offd = 1; offd < 256; offd <<= 1) {
        int v = (tid >= offd) ? incl[tid - offd] : 0;
        __syncthreads();
        incl[tid] += v;
        __syncthreads();
    }
    if (blockIdx.x == 0 && tid == 0) {
        int tot = incl[NWORDS - 1];
        knum[0] = tot < CAND_CAP ? tot : CAND_CAP;
    }
    int i = blockIdx.x * 256 + tid;
    int w = i >> 6, l = i & 63;
    unsigned long long bits = rnz64[w];
    if (bits & (1ull << l)) {
        int base = incl[w] - (int)__popcll(bits);   // exclusive prefix of word w
        int pos = base + (int)__popcll(bits & ((1ull << l) - 1ull));
        if (pos < CAND_CAP) {
            cidx[pos] = i;
            cboxes[pos] = ((const float4*)sboxes)[i];
            carea[pos] = sareas[i];
        }
    }
}

// ---------------- candidate x candidate gating matrix + diagonal strips ----------------
__global__ __launch_bounds__(256) void gate_build(const float4* __restrict__ cboxes,
                                                  const float* __restrict__ carea,
                                                  const int* __restrict__ knum,
                                                  unsigned long long* __restrict__ gate,
                                                  unsigned long long* __restrict__ diag0,
                                                  unsigned long long* __restrict__ diag1) {
    int Kc = knum[0];
    int a = blockIdx.x * 4 + (threadIdx.x >> 6);
    int w = threadIdx.x & 63;
    if (a >= Kc) return;
    float4 b = cboxes[a];
    float ar = carea[a];
    unsigned long long bits = 0ull;
    int cbase = w * 64;
    if (cbase < Kc) {
        int lim = Kc - cbase; if (lim > 64) lim = 64;
        for (int t = 0; t < lim; ++t) {
            int c = cbase + t;
            if (c > a) {
                float4 cb = cboxes[c];
                float ix = fminf(b.z, cb.z) - fmaxf(b.x, cb.x);
                float iy = fminf(b.w, cb.w) - fmaxf(b.y, cb.y);
                float inter = fmaxf(ix, 0.f) * fmaxf(iy, 0.f);
                float denom = ar + carea[c] - inter;
                if (inter > 0.85f * denom && denom >= 0.f) {
                    if (inter / denom > IOU_THRF) bits |= (1ull << t);
                }
            }
        }
    }
    gate[(size_t)a * 64 + w] = bits;
    int aw = a >> 6;
    if (w == aw) diag0[a] = bits;
    if (w == aw + 1) diag1[a] = bits;
}

// ---------------- serial greedy scan: LDS strips, lazy full-row OR ----------------
__global__ __launch_bounds__(512) void nms_scan5(const unsigned long long* __restrict__ gate,
                                                 const unsigned long long* __restrict__ diag0,
                                                 const unsigned long long* __restrict__ diag1,
                                                 const int* __restrict__ knum,
                                                 int* __restrict__ fire_ord,
                                                 int* __restrict__ fire_cnt) {
    __shared__ unsigned long long d0L[CAND_CAP];   // 32 KB
    __shared__ unsigned long long d1L[CAND_CAP];   // 32 KB
    __shared__ unsigned long long supL[64];
    __shared__ int flist[2][64];
    __shared__ int fcnt[2];
    int tid = threadIdx.x;
    int Kc = knum[0];
    int nw = (Kc + 63) >> 6;

    #pragma unroll
    for (int q = 0; q < CAND_CAP / 512; ++q) {
        d0L[tid + 512 * q] = diag0[tid + 512 * q];
        d1L[tid + 512 * q] = diag1[tid + 512 * q];
    }
    if (tid < 64) supL[tid] = 0ull;
    if (tid == 0) { fcnt[0] = 0; fcnt[1] = 0; }
    __syncthreads();

    int nf = 0;                       // wave0-uniform
    unsigned long long carry = 0ull;  // wave0-uniform

    for (int w = 0; w < nw; ++w) {
        if (tid >= 64) {
            int wv = (tid >> 6) - 1;        // 0..6
            int j = tid & 63;
            int fp = fcnt[(w + 1) & 1];
            for (int f = wv; f < fp; f += 7) {
                int o = flist[(w + 1) & 1][f];
                if (j < nw) {
                    unsigned long long g = gate[(size_t)o * 64 + j];
                    if (g) atomicOr(&supL[j], g);
                }
            }
        } else {
            int rem = Kc - (w << 6);
            unsigned long long maskw = (rem >= 64) ? ~0ull : ((1ull << rem) - 1ull);
            unsigned long long alive = ~(supL[w] | carry) & maskw;
            unsigned long long carry_next = 0ull;
            int myf = 0;
            while (alive) {
                int t = __builtin_ctzll(alive);
                int o = (w << 6) + t;
                if (tid == 0) {
                    if (nf < FIRE_CAP) fire_ord[nf] = o;
                    flist[w & 1][myf] = o;
                }
                ++nf; ++myf;
                unsigned long long dd0 = d0L[o];
                unsigned long long dd1 = d1L[o];
                alive &= ~(1ull << t);
                alive &= ~dd0;
                carry_next |= dd1;
            }
            if (tid == 0) fcnt[w & 1] = myf;
            carry = carry_next;
        }
        __syncthreads();
    }
    if (tid == 0) fire_cnt[0] = nf < FIRE_CAP ? nf : FIRE_CAP;
}

// ---------------- finalize: recompute suppression vs fires, write output ----------------
__global__ __launch_bounds__(256) void finalize(const float* __restrict__ sboxes,
                                                const float* __restrict__ sareas,
                                                const float* __restrict__ scores,
                                                const int* __restrict__ order,
                                                const float4* __restrict__ cboxes,
                                                const float* __restrict__ carea,
                                                const int* __restrict__ cidx,
                                                const int* __restrict__ fire_ord,
                                                const int* __restrict__ fire_cnt,
                                                float* __restrict__ out) {
    __shared__ float4 FB[FIRE_CAP];
    __shared__ float FA[FIRE_CAP];
    __shared__ int FP[FIRE_CAP];
    int tid = threadIdx.x;
    int fc = fire_cnt[0];
    for (int k = tid; k < fc; k += 256) {
        int o = fire_ord[k];
        FB[k] = cboxes[o];
        FA[k] = carea[o];
        FP[k] = cidx[o];
    }
    __syncthreads();
    int j = blockIdx.x * 256 + tid;   // sorted index
    float4 b = ((const float4*)sboxes)[j];
    float aj = sareas[j];
    bool supp = false;
    for (int k = 0; k < fc; ++k) {
        float4 f = FB[k];
        float ix = fminf(b.z, f.z) - fmaxf(b.x, f.x);
        float iy = fminf(b.w, f.w) - fmaxf(b.y, f.y);
        float inter = fmaxf(ix, 0.f) * fmaxf(iy, 0.f);
        float denom = FA[k] + aj - inter;
        if (FP[k] < j && inter > 0.85f * denom && denom >= 0.f) {
            if (inter / denom > IOU_THRF) supp = true;
        }
    }
    int n = order[j];
    float m = supp ? 0.f : 1.f;
    out[(size_t)n * 5 + 0] = b.x * m;
    out[(size_t)n * 5 + 1] = b.y * m;
    out[(size_t)n * 5 + 2] = b.z * m;
    out[(size_t)n * 5 + 3] = b.w * m;
    out[(size_t)n * 5 + 4] = scores[n] * m;
}

extern "C" void kernel_launch(void* const* d_in, const int* in_sizes, int n_in,
                              void* d_out, int out_size, void* d_ws, size_t ws_size,
                              hipStream_t stream) {
    const float* x      = (const float*)d_in[0];
    const float* anchors= (const float*)d_in[1];
    const float* dw_w   = (const float*)d_in[2];
    const float* pw_w   = (const float*)d_in[3];
    const float* bn1g   = (const float*)d_in[4];
    const float* bn1b   = (const float*)d_in[5];
    const float* bn1m   = (const float*)d_in[6];
    const float* bn1v   = (const float*)d_in[7];
    const float* anc_w  = (const float*)d_in[8];
    const float* ag     = (const float*)d_in[9];
    const float* ab     = (const float*)d_in[10];
    const float* am     = (const float*)d_in[11];
    const float* av     = (const float*)d_in[12];
    const float* obj_w  = (const float*)d_in[13];
    const float* og     = (const float*)d_in[14];
    const float* ob     = (const float*)d_in[15];
    const float* om     = (const float*)d_in[16];
    const float* ov     = (const float*)d_in[17];
    float* out = (float*)d_out;

    char* ws = (char*)d_ws;
    size_t off = 0;
    auto alloc = [&](size_t bytes) -> char* {
        char* p = ws + off;
        off = (off + bytes + 255) & ~(size_t)255;
        return p;
    };
    float* h0      = (float*)alloc(256 * 1024 * 4);
    float* h1      = (float*)alloc(256 * 1024 * 4);
    float* boxes   = (float*)alloc(NBOX * 4 * 4);
    float* scores  = (float*)alloc(NBOX * 4);
    unsigned* rank = (unsigned*)alloc(NBOX * 4);
    int* order     = (int*)alloc(NBOX * 4);
    float* sboxes  = (float*)alloc(NBOX * 4 * 4);
    float* sareas  = (float*)alloc(NBOX * 4);
    unsigned long long* rnz64 = (unsigned long long*)alloc(192 * 8);
    int* cidx      = (int*)alloc(CAND_CAP * 4);
    float4* cboxes = (float4*)alloc(CAND_CAP * 16);
    float* carea   = (float*)alloc(CAND_CAP * 4);
    int* knum      = (int*)alloc(256);
    int* fire_ord  = (int*)alloc(FIRE_CAP * 4);
    int* fire_cnt  = (int*)alloc(256);
    unsigned long long* gate  = (unsigned long long*)alloc((size_t)CAND_CAP * 64 * 8);
    unsigned long long* diag0 = (unsigned long long*)alloc(CAND_CAP * 8);
    unsigned long long* diag1 = (unsigned long long*)alloc(CAND_CAP * 8);

    hipMemsetAsync(rank, 0, NBOX * 4, stream);
    hipMemsetAsync(rnz64, 0, 192 * 8, stream);

    dw_conv<<<1024, 256, 0, stream>>>(x, dw_w, h0);
    pw_conv<<<dim3(4, 64), 256, 0, stream>>>(h0, pw_w, bn1g, bn1b, bn1m, bn1v, h1);
    heads<<<dim3(4, 45), 256, 0, stream>>>(h1, anc_w, ag, ab, am, av,
                                           obj_w, og, ob, om, ov, anchors, boxes, scores);
    rank_partial<<<dim3(36, 16), 256, 0, stream>>>(scores, rank);
    scatter_sorted<<<36, 256, 0, stream>>>(boxes, rank, order, sboxes, sareas);
    cand_detect<<<CD_TILES, 256, 0, stream>>>(sboxes, sareas, rnz64);
    compact_cand2<<<36, 256, 0, stream>>>(rnz64, sboxes, sareas, cidx, cboxes, carea, knum);
    gate_build<<<CAND_CAP / 4, 256, 0, stream>>>(cboxes, carea, knum, gate, diag0, diag1);
    nms_scan5<<<1, 512, 0, stream>>>(gate, diag0, diag1, knum, fire_ord, fire_cnt);
    finalize<<<36, 256, 0, stream>>>(sboxes, sareas, scores, order,
                                     cboxes, carea, cidx, fire_ord, fire_cnt, out);
}

// Round 16
// 322.108 us; speedup vs baseline: 1.1133x; 1.1133x over previous
//
#include <hip/hip_runtime.h>
#include <hip/hip_bf16.h>

#define EPSF 1e-5f
#define IOU_THRF 0.9f
#define NBOX 9216
#define NWORDS 144   // 9216/64
#define CAND_CAP 4096
#define FIRE_CAP 1024
#define CD_TILES 1332  // 256-row x 128-col upper-tri tiles: sum_{rb=0..35}(72-2rb)

// ---------------- depthwise 3x3 conv, C=256, 32x32, pad 1 ----------------
__global__ __launch_bounds__(256) void dw_conv(const float* __restrict__ x,
                                               const float* __restrict__ w,
                                               float* __restrict__ h0) {
    int idx = blockIdx.x * 256 + threadIdx.x;   // 262144 threads
    int c = idx >> 10, p = idx & 1023;
    int yy = p >> 5, xx = p & 31;
    const float* xi = x + (c << 10);
    const float* wc = w + c * 9;
    float acc = 0.f;
    #pragma unroll
    for (int dy = -1; dy <= 1; ++dy) {
        int y2 = yy + dy;
        if ((unsigned)y2 >= 32u) continue;
        #pragma unroll
        for (int dx = -1; dx <= 1; ++dx) {
            int x2 = xx + dx;
            if ((unsigned)x2 >= 32u) continue;
            acc += wc[(dy + 1) * 3 + (dx + 1)] * xi[y2 * 32 + x2];
        }
    }
    h0[idx] = acc;
}

// ---------------- pointwise 256x256 GEMM + BN1 + leaky relu ----------------
__global__ __launch_bounds__(256) void pw_conv(const float* __restrict__ h0,
                                               const float* __restrict__ w,
                                               const float* __restrict__ g,
                                               const float* __restrict__ b,
                                               const float* __restrict__ mu,
                                               const float* __restrict__ var,
                                               float* __restrict__ h1) {
    int p = blockIdx.x * 256 + threadIdx.x;
    int o0 = blockIdx.y * 4;
    float acc0 = 0.f, acc1 = 0.f, acc2 = 0.f, acc3 = 0.f;
    for (int c = 0; c < 256; ++c) {
        float hv = h0[(c << 10) + p];
        acc0 += w[(o0 + 0) * 256 + c] * hv;
        acc1 += w[(o0 + 1) * 256 + c] * hv;
        acc2 += w[(o0 + 2) * 256 + c] * hv;
        acc3 += w[(o0 + 3) * 256 + c] * hv;
    }
    float accs[4] = {acc0, acc1, acc2, acc3};
    #pragma unroll
    for (int k = 0; k < 4; ++k) {
        int o = o0 + k;
        float inv = 1.0f / sqrtf(var[o] + EPSF);
        float v = (accs[k] - mu[o]) * (inv * g[o]) + b[o];
        v = (v >= 0.f) ? v : 0.01f * v;
        h1[(o << 10) + p] = v;
    }
}

// ---------------- heads: anc (36 ch) + obj (9 ch) GEMV + BN + decode ----------------
__global__ __launch_bounds__(256) void heads(const float* __restrict__ h1,
                                             const float* __restrict__ anc_w,
                                             const float* __restrict__ ag,
                                             const float* __restrict__ ab,
                                             const float* __restrict__ am,
                                             const float* __restrict__ av,
                                             const float* __restrict__ obj_w,
                                             const float* __restrict__ og,
                                             const float* __restrict__ ob,
                                             const float* __restrict__ om,
                                             const float* __restrict__ ov,
                                             const float* __restrict__ anchors,
                                             float* __restrict__ boxes,
                                             float* __restrict__ scores) {
    int p = blockIdx.x * 256 + threadIdx.x;
    int o = blockIdx.y;
    const float* wrow = (o < 36) ? (anc_w + o * 256) : (obj_w + (o - 36) * 256);
    float acc = 0.f;
    for (int c = 0; c < 256; ++c) acc += wrow[c] * h1[(c << 10) + p];
    if (o < 36) {
        float inv = 1.0f / sqrtf(av[o] + EPSF);
        float v = (acc - am[o]) * (inv * ag[o]) + ab[o];
        v = fminf(fmaxf(v, 0.f), 6.f);           // clip 0..6
        int a = o >> 2, k = o & 3;
        float anch = anchors[a * 4 + k];
        float val = (k < 2) ? (v + anch) : (expf(v) * anch);
        boxes[(size_t)(a * 1024 + p) * 4 + k] = val;
    } else {
        int a = o - 36;
        float inv = 1.0f / sqrtf(ov[a] + EPSF);
        float v = (acc - om[a]) * (inv * og[a]) + ob[a];
        scores[a * 1024 + p] = 1.0f / (1.0f + expf(-v));
    }
}

// ---------------- rank = stable-descending-argsort position, O(N^2) count ----------------
__global__ __launch_bounds__(256) void rank_partial(const float* __restrict__ scores,
                                                    unsigned* __restrict__ rank) {
    __shared__ float4 sm[144];
    int mbase = blockIdx.y * 576;
    for (int t = threadIdx.x; t < 144; t += 256)
        sm[t] = ((const float4*)(scores + mbase))[t];
    __syncthreads();
    int n = blockIdx.x * 256 + threadIdx.x;
    float s = scores[n];
    unsigned cnt = 0;
    for (int q = 0; q < 144; ++q) {
        float4 v = sm[q];
        int m = mbase + q * 4;
        cnt += (v.x > s) || (v.x == s && (m + 0) < n);
        cnt += (v.y > s) || (v.y == s && (m + 1) < n);
        cnt += (v.z > s) || (v.z == s && (m + 2) < n);
        cnt += (v.w > s) || (v.w == s && (m + 3) < n);
    }
    atomicAdd(&rank[n], cnt);
}

// ---------------- scatter into sorted order ----------------
__global__ __launch_bounds__(256) void scatter_sorted(const float* __restrict__ boxes,
                                                      const unsigned* __restrict__ rank,
                                                      int* __restrict__ order,
                                                      float* __restrict__ sboxes,
                                                      float* __restrict__ sareas) {
    int n = blockIdx.x * 256 + threadIdx.x;
    unsigned r = rank[n];
    order[r] = n;
    float4 bx = ((const float4*)boxes)[n];
    ((float4*)sboxes)[r] = bx;
    sareas[r] = (bx.z - bx.x) * (bx.w - bx.y);
}

// ---------------- candidate detection, ballot-guarded exact division ----------------
// 1332 tiles of 256 rows x 128 cols, 1 row/thread. Per pair: 13-op screen
// near = (t > 0.85*d) && (d >= 0)  [near <=> iou ~> 0.85; d<0 => iou<=0;
// d==0 & t>0 => near => division gives +inf = reference hit]. Division (exact
// reference formula) only runs when __any(near) — wave-uniformly skipped for
// ~99.9% of columns. No row-level redo loops, no pend state.
__global__ __launch_bounds__(256) void cand_detect(const float* __restrict__ sboxes,
                                                   const float* __restrict__ sareas,
                                                   unsigned long long* __restrict__ rnz64) {
    __shared__ float4 B4[128];
    __shared__ float CARs[128];
    int rem = blockIdx.x, rg = 0;
    while (rem >= 72 - 2 * rg) { rem -= 72 - 2 * rg; ++rg; }
    int sc = 2 * rg + rem;   // col block (128 wide), sc >= 2*rg
    int tid = threadIdx.x;
    if (tid < 128) {
        int j = sc * 128 + tid;
        B4[tid] = ((const float4*)sboxes)[j];
        CARs[tid] = sareas[j];
    }
    __syncthreads();
    int i = rg * 256 + tid;
    float4 b = ((const float4*)sboxes)[i];
    float ar = sareas[i];
    bool cand = false;

    if (sc >= 2 * rg + 2) {
        // all j > i guaranteed
        #pragma unroll 4
        for (int idx = 0; idx < 128; ++idx) {
            float4 cb = B4[idx]; float aa = CARs[idx];
            float ix = fminf(b.z, cb.z) - fmaxf(b.x, cb.x);
            float iy = fminf(b.w, cb.w) - fmaxf(b.y, cb.y);
            float t = fmaxf(ix, 0.f) * fmaxf(iy, 0.f);
            float d = ar + aa - t;
            bool near = (t > 0.85f * d) && (d >= 0.f);
            if (__any(near)) {                       // rare, wave-uniform
                cand = cand || (near && (t / d > IOU_THRF));   // exact ref division
            }
        }
    } else {
        #pragma unroll 4
        for (int idx = 0; idx < 128; ++idx) {
            int j = sc * 128 + idx;
            float4 cb = B4[idx]; float aa = CARs[idx];
            float ix = fminf(b.z, cb.z) - fmaxf(b.x, cb.x);
            float iy = fminf(b.w, cb.w) - fmaxf(b.y, cb.y);
            float t = fmaxf(ix, 0.f) * fmaxf(iy, 0.f);
            float d = ar + aa - t;
            bool near = (j > i) && (t > 0.85f * d) && (d >= 0.f);
            if (__any(near)) {
                cand = cand || (near && (t / d > IOU_THRF));
            }
        }
    }
    unsigned long long bal = __ballot(cand);
    if ((tid & 63) == 0) atomicOr(&rnz64[rg * 4 + (tid >> 6)], bal);
}

__device__ inline unsigned long long rdl64(unsigned long long v, int l) {
    unsigned lo = (unsigned)__builtin_amdgcn_readlane((int)(unsigned)(v & 0xffffffffull), l);
    unsigned hi = (unsigned)__builtin_amdgcn_readlane((int)(unsigned)(v >> 32), l);
    return ((unsigned long long)hi << 32) | lo;
}

// ---------------- compact candidates, PARALLEL (36 blocks) ----------------
__global__ __launch_bounds__(256) void compact_cand2(const unsigned long long* __restrict__ rnz64,
                                                     const float* __restrict__ sboxes,
                                                     const float* __restrict__ sareas,
                                                     int* __restrict__ cidx,
                                                     float4* __restrict__ cboxes,
                                                     float* __restrict__ carea,
                                                     int* __restrict__ knum) {
    __shared__ int incl[256];
    int tid = threadIdx.x;
    int myc = (tid < NWORDS) ? (int)__popcll(rnz64[tid]) : 0;
    incl[tid] = myc;
    __syncthreads();
    #pragma unroll
    for (int offd = 1; offd < 256; offd <<= 1) {
        int v = (tid >= offd) ? incl[tid - offd] : 0;
        __syncthreads();
        incl[tid] += v;
        __syncthreads();
    }
    if (blockIdx.x == 0 && tid == 0) {
        int tot = incl[NWORDS - 1];
        knum[0] = tot < CAND_CAP ? tot : CAND_CAP;
    }
    int i = blockIdx.x * 256 + tid;
    int w = i >> 6, l = i & 63;
    unsigned long long bits = rnz64[w];
    if (bits & (1ull << l)) {
        int base = incl[w] - (int)__popcll(bits);   // exclusive prefix of word w
        int pos = base + (int)__popcll(bits & ((1ull << l) - 1ull));
        if (pos < CAND_CAP) {
            cidx[pos] = i;
            cboxes[pos] = ((const float4*)sboxes)[i];
            carea[pos] = sareas[i];
        }
    }
}

// ---------------- candidate x candidate gating matrix + diagonal strips ----------------
__global__ __launch_bounds__(256) void gate_build(const float4* __restrict__ cboxes,
                                                  const float* __restrict__ carea,
                                                  const int* __restrict__ knum,
                                                  unsigned long long* __restrict__ gate,
                                                  unsigned long long* __restrict__ diag0,
                                                  unsigned long long* __restrict__ diag1) {
    int Kc = knum[0];
    int a = blockIdx.x * 4 + (threadIdx.x >> 6);
    int w = threadIdx.x & 63;
    if (a >= Kc) return;
    float4 b = cboxes[a];
    float ar = carea[a];
    unsigned long long bits = 0ull;
    int cbase = w * 64;
    if (cbase < Kc) {
        int lim = Kc - cbase; if (lim > 64) lim = 64;
        for (int t = 0; t < lim; ++t) {
            int c = cbase + t;
            if (c > a) {
                float4 cb = cboxes[c];
                float ix = fminf(b.z, cb.z) - fmaxf(b.x, cb.x);
                float iy = fminf(b.w, cb.w) - fmaxf(b.y, cb.y);
                float inter = fmaxf(ix, 0.f) * fmaxf(iy, 0.f);
                float denom = ar + carea[c] - inter;
                if (inter > 0.85f * denom && denom >= 0.f) {
                    if (inter / denom > IOU_THRF) bits |= (1ull << t);
                }
            }
        }
    }
    gate[(size_t)a * 64 + w] = bits;
    int aw = a >> 6;
    if (w == aw) diag0[a] = bits;
    if (w == aw + 1) diag1[a] = bits;
}

// ---------------- serial greedy scan: LDS strips, lazy full-row OR ----------------
__global__ __launch_bounds__(512) void nms_scan5(const unsigned long long* __restrict__ gate,
                                                 const unsigned long long* __restrict__ diag0,
                                                 const unsigned long long* __restrict__ diag1,
                                                 const int* __restrict__ knum,
                                                 int* __restrict__ fire_ord,
                                                 int* __restrict__ fire_cnt) {
    __shared__ unsigned long long d0L[CAND_CAP];   // 32 KB
    __shared__ unsigned long long d1L[CAND_CAP];   // 32 KB
    __shared__ unsigned long long supL[64];
    __shared__ int flist[2][64];
    __shared__ int fcnt[2];
    int tid = threadIdx.x;
    int Kc = knum[0];
    int nw = (Kc + 63) >> 6;

    #pragma unroll
    for (int q = 0; q < CAND_CAP / 512; ++q) {
        d0L[tid + 512 * q] = diag0[tid + 512 * q];
        d1L[tid + 512 * q] = diag1[tid + 512 * q];
    }
    if (tid < 64) supL[tid] = 0ull;
    if (tid == 0) { fcnt[0] = 0; fcnt[1] = 0; }
    __syncthreads();

    int nf = 0;                       // wave0-uniform
    unsigned long long carry = 0ull;  // wave0-uniform

    for (int w = 0; w < nw; ++w) {
        if (tid >= 64) {
            int wv = (tid >> 6) - 1;        // 0..6
            int j = tid & 63;
            int fp = fcnt[(w + 1) & 1];
            for (int f = wv; f < fp; f += 7) {
                int o = flist[(w + 1) & 1][f];
                if (j < nw) {
                    unsigned long long g = gate[(size_t)o * 64 + j];
                    if (g) atomicOr(&supL[j], g);
                }
            }
        } else {
            int rem = Kc - (w << 6);
            unsigned long long maskw = (rem >= 64) ? ~0ull : ((1ull << rem) - 1ull);
            unsigned long long alive = ~(supL[w] | carry) & maskw;
            unsigned long long carry_next = 0ull;
            int myf = 0;
            while (alive) {
                int t = __builtin_ctzll(alive);
                int o = (w << 6) + t;
                if (tid == 0) {
                    if (nf < FIRE_CAP) fire_ord[nf] = o;
                    flist[w & 1][myf] = o;
                }
                ++nf; ++myf;
                unsigned long long dd0 = d0L[o];
                unsigned long long dd1 = d1L[o];
                alive &= ~(1ull << t);
                alive &= ~dd0;
                carry_next |= dd1;
            }
            if (tid == 0) fcnt[w & 1] = myf;
            carry = carry_next;
        }
        __syncthreads();
    }
    if (tid == 0) fire_cnt[0] = nf < FIRE_CAP ? nf : FIRE_CAP;
}

// ---------------- finalize: recompute suppression vs fires, write output ----------------
__global__ __launch_bounds__(256) void finalize(const float* __restrict__ sboxes,
                                                const float* __restrict__ sareas,
                                                const float* __restrict__ scores,
                                                const int* __restrict__ order,
                                                const float4* __restrict__ cboxes,
                                                const float* __restrict__ carea,
                                                const int* __restrict__ cidx,
                                                const int* __restrict__ fire_ord,
                                                const int* __restrict__ fire_cnt,
                                                float* __restrict__ out) {
    __shared__ float4 FB[FIRE_CAP];
    __shared__ float FA[FIRE_CAP];
    __shared__ int FP[FIRE_CAP];
    int tid = threadIdx.x;
    int fc = fire_cnt[0];
    for (int k = tid; k < fc; k += 256) {
        int o = fire_ord[k];
        FB[k] = cboxes[o];
        FA[k] = carea[o];
        FP[k] = cidx[o];
    }
    __syncthreads();
    int j = blockIdx.x * 256 + tid;   // sorted index
    float4 b = ((const float4*)sboxes)[j];
    float aj = sareas[j];
    bool supp = false;
    for (int k = 0; k < fc; ++k) {
        float4 f = FB[k];
        float ix = fminf(b.z, f.z) - fmaxf(b.x, f.x);
        float iy = fminf(b.w, f.w) - fmaxf(b.y, f.y);
        float inter = fmaxf(ix, 0.f) * fmaxf(iy, 0.f);
        float denom = FA[k] + aj - inter;
        if (FP[k] < j && inter > 0.85f * denom && denom >= 0.f) {
            if (inter / denom > IOU_THRF) supp = true;
        }
    }
    int n = order[j];
    float m = supp ? 0.f : 1.f;
    out[(size_t)n * 5 + 0] = b.x * m;
    out[(size_t)n * 5 + 1] = b.y * m;
    out[(size_t)n * 5 + 2] = b.z * m;
    out[(size_t)n * 5 + 3] = b.w * m;
    out[(size_t)n * 5 + 4] = scores[n] * m;
}

extern "C" void kernel_launch(void* const* d_in, const int* in_sizes, int n_in,
                              void* d_out, int out_size, void* d_ws, size_t ws_size,
                              hipStream_t stream) {
    const float* x      = (const float*)d_in[0];
    const float* anchors= (const float*)d_in[1];
    const float* dw_w   = (const float*)d_in[2];
    const float* pw_w   = (const float*)d_in[3];
    const float* bn1g   = (const float*)d_in[4];
    const float* bn1b   = (const float*)d_in[5];
    const float* bn1m   = (const float*)d_in[6];
    const float* bn1v   = (const float*)d_in[7];
    const float* anc_w  = (const float*)d_in[8];
    const float* ag     = (const float*)d_in[9];
    const float* ab     = (const float*)d_in[10];
    const float* am     = (const float*)d_in[11];
    const float* av     = (const float*)d_in[12];
    const float* obj_w  = (const float*)d_in[13];
    const float* og     = (const float*)d_in[14];
    const float* ob     = (const float*)d_in[15];
    const float* om     = (const float*)d_in[16];
    const float* ov     = (const float*)d_in[17];
    float* out = (float*)d_out;

    char* ws = (char*)d_ws;
    size_t off = 0;
    auto alloc = [&](size_t bytes) -> char* {
        char* p = ws + off;
        off = (off + bytes + 255) & ~(size_t)255;
        return p;
    };
    float* h0      = (float*)alloc(256 * 1024 * 4);
    float* h1      = (float*)alloc(256 * 1024 * 4);
    float* boxes   = (float*)alloc(NBOX * 4 * 4);
    float* scores  = (float*)alloc(NBOX * 4);
    unsigned* rank = (unsigned*)alloc(NBOX * 4);
    int* order     = (int*)alloc(NBOX * 4);
    float* sboxes  = (float*)alloc(NBOX * 4 * 4);
    float* sareas  = (float*)alloc(NBOX * 4);
    unsigned long long* rnz64 = (unsigned long long*)alloc(192 * 8);
    int* cidx      = (int*)alloc(CAND_CAP * 4);
    float4* cboxes = (float4*)alloc(CAND_CAP * 16);
    float* carea   = (float*)alloc(CAND_CAP * 4);
    int* knum      = (int*)alloc(256);
    int* fire_ord  = (int*)alloc(FIRE_CAP * 4);
    int* fire_cnt  = (int*)alloc(256);
    unsigned long long* gate  = (unsigned long long*)alloc((size_t)CAND_CAP * 64 * 8);
    unsigned long long* diag0 = (unsigned long long*)alloc(CAND_CAP * 8);
    unsigned long long* diag1 = (unsigned long long*)alloc(CAND_CAP * 8);

    hipMemsetAsync(rank, 0, NBOX * 4, stream);
    hipMemsetAsync(rnz64, 0, 192 * 8, stream);

    dw_conv<<<1024, 256, 0, stream>>>(x, dw_w, h0);
    pw_conv<<<dim3(4, 64), 256, 0, stream>>>(h0, pw_w, bn1g, bn1b, bn1m, bn1v, h1);
    heads<<<dim3(4, 45), 256, 0, stream>>>(h1, anc_w, ag, ab, am, av,
                                           obj_w, og, ob, om, ov, anchors, boxes, scores);
    rank_partial<<<dim3(36, 16), 256, 0, stream>>>(scores, rank);
    scatter_sorted<<<36, 256, 0, stream>>>(boxes, rank, order, sboxes, sareas);
    cand_detect<<<CD_TILES, 256, 0, stream>>>(sboxes, sareas, rnz64);
    compact_cand2<<<36, 256, 0, stream>>>(rnz64, sboxes, sareas, cidx, cboxes, carea, knum);
    gate_build<<<CAND_CAP / 4, 256, 0, stream>>>(cboxes, carea, knum, gate, diag0, diag1);
    nms_scan5<<<1, 512, 0, stream>>>(gate, diag0, diag1, knum, fire_ord, fire_cnt);
    finalize<<<36, 256, 0, stream>>>(sboxes, sareas, scores, order,
                                     cboxes, carea, cidx, fire_ord, fire_cnt, out);
}

// Round 17
// 320.269 us; speedup vs baseline: 1.1197x; 1.0057x over previous
//
#include <hip/hip_runtime.h>
#include <hip/hip_bf16.h>

#define EPSF 1e-5f
#define IOU_THRF 0.9f
#define NBOX 9216
#define NWORDS 144   // 9216/64
#define CAND_CAP 4096
#define FIRE_CAP 1024
#define CD_TILES 1332  // 256-row x 128-col upper-tri tiles: sum_{rb=0..35}(72-2rb)

// ---------------- depthwise 3x3 conv, C=256, 32x32, pad 1 ----------------
__global__ __launch_bounds__(256) void dw_conv(const float* __restrict__ x,
                                               const float* __restrict__ w,
                                               float* __restrict__ h0) {
    int idx = blockIdx.x * 256 + threadIdx.x;   // 262144 threads
    int c = idx >> 10, p = idx & 1023;
    int yy = p >> 5, xx = p & 31;
    const float* xi = x + (c << 10);
    const float* wc = w + c * 9;
    float acc = 0.f;
    #pragma unroll
    for (int dy = -1; dy <= 1; ++dy) {
        int y2 = yy + dy;
        if ((unsigned)y2 >= 32u) continue;
        #pragma unroll
        for (int dx = -1; dx <= 1; ++dx) {
            int x2 = xx + dx;
            if ((unsigned)x2 >= 32u) continue;
            acc += wc[(dy + 1) * 3 + (dx + 1)] * xi[y2 * 32 + x2];
        }
    }
    h0[idx] = acc;
}

// ---------------- pointwise 256x256 GEMM + BN1 + leaky relu ----------------
__global__ __launch_bounds__(256) void pw_conv(const float* __restrict__ h0,
                                               const float* __restrict__ w,
                                               const float* __restrict__ g,
                                               const float* __restrict__ b,
                                               const float* __restrict__ mu,
                                               const float* __restrict__ var,
                                               float* __restrict__ h1) {
    int p = blockIdx.x * 256 + threadIdx.x;
    int o0 = blockIdx.y * 4;
    float acc0 = 0.f, acc1 = 0.f, acc2 = 0.f, acc3 = 0.f;
    for (int c = 0; c < 256; ++c) {
        float hv = h0[(c << 10) + p];
        acc0 += w[(o0 + 0) * 256 + c] * hv;
        acc1 += w[(o0 + 1) * 256 + c] * hv;
        acc2 += w[(o0 + 2) * 256 + c] * hv;
        acc3 += w[(o0 + 3) * 256 + c] * hv;
    }
    float accs[4] = {acc0, acc1, acc2, acc3};
    #pragma unroll
    for (int k = 0; k < 4; ++k) {
        int o = o0 + k;
        float inv = 1.0f / sqrtf(var[o] + EPSF);
        float v = (accs[k] - mu[o]) * (inv * g[o]) + b[o];
        v = (v >= 0.f) ? v : 0.01f * v;
        h1[(o << 10) + p] = v;
    }
}

// ---------------- heads: anc (36 ch) + obj (9 ch) GEMV + BN + decode ----------------
__global__ __launch_bounds__(256) void heads(const float* __restrict__ h1,
                                             const float* __restrict__ anc_w,
                                             const float* __restrict__ ag,
                                             const float* __restrict__ ab,
                                             const float* __restrict__ am,
                                             const float* __restrict__ av,
                                             const float* __restrict__ obj_w,
                                             const float* __restrict__ og,
                                             const float* __restrict__ ob,
                                             const float* __restrict__ om,
                                             const float* __restrict__ ov,
                                             const float* __restrict__ anchors,
                                             float* __restrict__ boxes,
                                             float* __restrict__ scores) {
    int p = blockIdx.x * 256 + threadIdx.x;
    int o = blockIdx.y;
    const float* wrow = (o < 36) ? (anc_w + o * 256) : (obj_w + (o - 36) * 256);
    float acc = 0.f;
    for (int c = 0; c < 256; ++c) acc += wrow[c] * h1[(c << 10) + p];
    if (o < 36) {
        float inv = 1.0f / sqrtf(av[o] + EPSF);
        float v = (acc - am[o]) * (inv * ag[o]) + ab[o];
        v = fminf(fmaxf(v, 0.f), 6.f);           // clip 0..6
        int a = o >> 2, k = o & 3;
        float anch = anchors[a * 4 + k];
        float val = (k < 2) ? (v + anch) : (expf(v) * anch);
        boxes[(size_t)(a * 1024 + p) * 4 + k] = val;
    } else {
        int a = o - 36;
        float inv = 1.0f / sqrtf(ov[a] + EPSF);
        float v = (acc - om[a]) * (inv * og[a]) + ob[a];
        scores[a * 1024 + p] = 1.0f / (1.0f + expf(-v));
    }
}

// ---------------- rank = stable-descending-argsort position, O(N^2) count ----------------
__global__ __launch_bounds__(256) void rank_partial(const float* __restrict__ scores,
                                                    unsigned* __restrict__ rank) {
    __shared__ float4 sm[144];
    int mbase = blockIdx.y * 576;
    for (int t = threadIdx.x; t < 144; t += 256)
        sm[t] = ((const float4*)(scores + mbase))[t];
    __syncthreads();
    int n = blockIdx.x * 256 + threadIdx.x;
    float s = scores[n];
    unsigned cnt = 0;
    for (int q = 0; q < 144; ++q) {
        float4 v = sm[q];
        int m = mbase + q * 4;
        cnt += (v.x > s) || (v.x == s && (m + 0) < n);
        cnt += (v.y > s) || (v.y == s && (m + 1) < n);
        cnt += (v.z > s) || (v.z == s && (m + 2) < n);
        cnt += (v.w > s) || (v.w == s && (m + 3) < n);
    }
    atomicAdd(&rank[n], cnt);
}

// ---------------- scatter into sorted order ----------------
__global__ __launch_bounds__(256) void scatter_sorted(const float* __restrict__ boxes,
                                                      const unsigned* __restrict__ rank,
                                                      int* __restrict__ order,
                                                      float* __restrict__ sboxes,
                                                      float* __restrict__ sareas) {
    int n = blockIdx.x * 256 + threadIdx.x;
    unsigned r = rank[n];
    order[r] = n;
    float4 bx = ((const float4*)boxes)[n];
    ((float4*)sboxes)[r] = bx;
    sareas[r] = (bx.z - bx.x) * (bx.w - bx.y);
}

// ---------------- candidate detection, ballot-guarded exact division ----------------
__global__ __launch_bounds__(256) void cand_detect(const float* __restrict__ sboxes,
                                                   const float* __restrict__ sareas,
                                                   unsigned long long* __restrict__ rnz64) {
    __shared__ float4 B4[128];
    __shared__ float CARs[128];
    int rem = blockIdx.x, rg = 0;
    while (rem >= 72 - 2 * rg) { rem -= 72 - 2 * rg; ++rg; }
    int sc = 2 * rg + rem;   // col block (128 wide), sc >= 2*rg
    int tid = threadIdx.x;
    if (tid < 128) {
        int j = sc * 128 + tid;
        B4[tid] = ((const float4*)sboxes)[j];
        CARs[tid] = sareas[j];
    }
    __syncthreads();
    int i = rg * 256 + tid;
    float4 b = ((const float4*)sboxes)[i];
    float ar = sareas[i];
    bool cand = false;

    if (sc >= 2 * rg + 2) {
        #pragma unroll 4
        for (int idx = 0; idx < 128; ++idx) {
            float4 cb = B4[idx]; float aa = CARs[idx];
            float ix = fminf(b.z, cb.z) - fmaxf(b.x, cb.x);
            float iy = fminf(b.w, cb.w) - fmaxf(b.y, cb.y);
            float t = fmaxf(ix, 0.f) * fmaxf(iy, 0.f);
            float d = ar + aa - t;
            bool near = (t > 0.85f * d) && (d >= 0.f);
            if (__any(near)) {
                cand = cand || (near && (t / d > IOU_THRF));
            }
        }
    } else {
        #pragma unroll 4
        for (int idx = 0; idx < 128; ++idx) {
            int j = sc * 128 + idx;
            float4 cb = B4[idx]; float aa = CARs[idx];
            float ix = fminf(b.z, cb.z) - fmaxf(b.x, cb.x);
            float iy = fminf(b.w, cb.w) - fmaxf(b.y, cb.y);
            float t = fmaxf(ix, 0.f) * fmaxf(iy, 0.f);
            float d = ar + aa - t;
            bool near = (j > i) && (t > 0.85f * d) && (d >= 0.f);
            if (__any(near)) {
                cand = cand || (near && (t / d > IOU_THRF));
            }
        }
    }
    unsigned long long bal = __ballot(cand);
    if ((tid & 63) == 0) atomicOr(&rnz64[rg * 4 + (tid >> 6)], bal);
}

__device__ inline unsigned long long rdl64(unsigned long long v, int l) {
    unsigned lo = (unsigned)__builtin_amdgcn_readlane((int)(unsigned)(v & 0xffffffffull), l);
    unsigned hi = (unsigned)__builtin_amdgcn_readlane((int)(unsigned)(v >> 32), l);
    return ((unsigned long long)hi << 32) | lo;
}

// ---------------- compact candidates, PARALLEL (36 blocks) ----------------
__global__ __launch_bounds__(256) void compact_cand2(const unsigned long long* __restrict__ rnz64,
                                                     const float* __restrict__ sboxes,
                                                     const float* __restrict__ sareas,
                                                     int* __restrict__ cidx,
                                                     float4* __restrict__ cboxes,
                                                     float* __restrict__ carea,
                                                     int* __restrict__ knum) {
    __shared__ int incl[256];
    int tid = threadIdx.x;
    int myc = (tid < NWORDS) ? (int)__popcll(rnz64[tid]) : 0;
    incl[tid] = myc;
    __syncthreads();
    #pragma unroll
    for (int offd = 1; offd < 256; offd <<= 1) {
        int v = (tid >= offd) ? incl[tid - offd] : 0;
        __syncthreads();
        incl[tid] += v;
        __syncthreads();
    }
    if (blockIdx.x == 0 && tid == 0) {
        int tot = incl[NWORDS - 1];
        knum[0] = tot < CAND_CAP ? tot : CAND_CAP;
    }
    int i = blockIdx.x * 256 + tid;
    int w = i >> 6, l = i & 63;
    unsigned long long bits = rnz64[w];
    if (bits & (1ull << l)) {
        int base = incl[w] - (int)__popcll(bits);   // exclusive prefix of word w
        int pos = base + (int)__popcll(bits & ((1ull << l) - 1ull));
        if (pos < CAND_CAP) {
            cidx[pos] = i;
            cboxes[pos] = ((const float4*)sboxes)[i];
            carea[pos] = sareas[i];
        }
    }
}

// ---------------- candidate x candidate gating matrix + diagonal strips ----------------
__global__ __launch_bounds__(256) void gate_build(const float4* __restrict__ cboxes,
                                                  const float* __restrict__ carea,
                                                  const int* __restrict__ knum,
                                                  unsigned long long* __restrict__ gate,
                                                  unsigned long long* __restrict__ diag0,
                                                  unsigned long long* __restrict__ diag1) {
    int Kc = knum[0];
    int a = blockIdx.x * 4 + (threadIdx.x >> 6);
    int w = threadIdx.x & 63;
    if (a >= Kc) return;
    float4 b = cboxes[a];
    float ar = carea[a];
    unsigned long long bits = 0ull;
    int cbase = w * 64;
    if (cbase < Kc) {
        int lim = Kc - cbase; if (lim > 64) lim = 64;
        for (int t = 0; t < lim; ++t) {
            int c = cbase + t;
            if (c > a) {
                float4 cb = cboxes[c];
                float ix = fminf(b.z, cb.z) - fmaxf(b.x, cb.x);
                float iy = fminf(b.w, cb.w) - fmaxf(b.y, cb.y);
                float inter = fmaxf(ix, 0.f) * fmaxf(iy, 0.f);
                float denom = ar + carea[c] - inter;
                if (inter > 0.85f * denom && denom >= 0.f) {
                    if (inter / denom > IOU_THRF) bits |= (1ull << t);
                }
            }
        }
    }
    gate[(size_t)a * 64 + w] = bits;
    int aw = a >> 6;
    if (w == aw) diag0[a] = bits;
    if (w == aw + 1) diag1[a] = bits;
}

// ---------------- serial greedy scan: LDS strips, lazy full-row OR ----------------
__global__ __launch_bounds__(512) void nms_scan5(const unsigned long long* __restrict__ gate,
                                                 const unsigned long long* __restrict__ diag0,
                                                 const unsigned long long* __restrict__ diag1,
                                                 const int* __restrict__ knum,
                                                 int* __restrict__ fire_ord,
                                                 int* __restrict__ fire_cnt) {
    __shared__ unsigned long long d0L[CAND_CAP];   // 32 KB
    __shared__ unsigned long long d1L[CAND_CAP];   // 32 KB
    __shared__ unsigned long long supL[64];
    __shared__ int flist[2][64];
    __shared__ int fcnt[2];
    int tid = threadIdx.x;
    int Kc = knum[0];
    int nw = (Kc + 63) >> 6;

    #pragma unroll
    for (int q = 0; q < CAND_CAP / 512; ++q) {
        d0L[tid + 512 * q] = diag0[tid + 512 * q];
        d1L[tid + 512 * q] = diag1[tid + 512 * q];
    }
    if (tid < 64) supL[tid] = 0ull;
    if (tid == 0) { fcnt[0] = 0; fcnt[1] = 0; }
    __syncthreads();

    int nf = 0;                       // wave0-uniform
    unsigned long long carry = 0ull;  // wave0-uniform

    for (int w = 0; w < nw; ++w) {
        if (tid >= 64) {
            int wv = (tid >> 6) - 1;        // 0..6
            int j = tid & 63;
            int fp = fcnt[(w + 1) & 1];
            for (int f = wv; f < fp; f += 7) {
                int o = flist[(w + 1) & 1][f];
                if (j < nw) {
                    unsigned long long g = gate[(size_t)o * 64 + j];
                    if (g) atomicOr(&supL[j], g);
                }
            }
        } else {
            int rem = Kc - (w << 6);
            unsigned long long maskw = (rem >= 64) ? ~0ull : ((1ull << rem) - 1ull);
            unsigned long long alive = ~(supL[w] | carry) & maskw;
            unsigned long long carry_next = 0ull;
            int myf = 0;
            while (alive) {
                int t = __builtin_ctzll(alive);
                int o = (w << 6) + t;
                if (tid == 0) {
                    if (nf < FIRE_CAP) fire_ord[nf] = o;
                    flist[w & 1][myf] = o;
                }
                ++nf; ++myf;
                unsigned long long dd0 = d0L[o];
                unsigned long long dd1 = d1L[o];
                alive &= ~(1ull << t);
                alive &= ~dd0;
                carry_next |= dd1;
            }
            if (tid == 0) fcnt[w & 1] = myf;
            carry = carry_next;
        }
        __syncthreads();
    }
    if (tid == 0) fire_cnt[0] = nf < FIRE_CAP ? nf : FIRE_CAP;
}

// ---------------- finalize v2: coalesced via inverse permutation (rank) ----------------
// Thread n handles OUTPUT row n directly: j = rank[n] (n's sorted position),
// box = boxes[n] (coalesced), aj recomputed with the identical fp expression
// used to build sareas. Suppression vs LDS-staged fires (FP[k] < j). Writes
// out[n*5..] — consecutive threads write consecutive 20B -> fully coalesced.
__global__ __launch_bounds__(256) void finalize(const float* __restrict__ boxes,
                                                const float* __restrict__ scores,
                                                const unsigned* __restrict__ rank,
                                                const float4* __restrict__ cboxes,
                                                const float* __restrict__ carea,
                                                const int* __restrict__ cidx,
                                                const int* __restrict__ fire_ord,
                                                const int* __restrict__ fire_cnt,
                                                float* __restrict__ out) {
    __shared__ float4 FB[FIRE_CAP];
    __shared__ float FA[FIRE_CAP];
    __shared__ int FP[FIRE_CAP];
    int tid = threadIdx.x;
    int fc = fire_cnt[0];
    for (int k = tid; k < fc; k += 256) {
        int o = fire_ord[k];
        FB[k] = cboxes[o];
        FA[k] = carea[o];
        FP[k] = cidx[o];
    }
    __syncthreads();
    int n = blockIdx.x * 256 + tid;   // output row
    int j = (int)rank[n];             // sorted position of box n
    float4 b = ((const float4*)boxes)[n];
    float aj = (b.z - b.x) * (b.w - b.y);   // identical expr to sareas build
    bool supp = false;
    for (int k = 0; k < fc; ++k) {
        float4 f = FB[k];
        float ix = fminf(b.z, f.z) - fmaxf(b.x, f.x);
        float iy = fminf(b.w, f.w) - fmaxf(b.y, f.y);
        float inter = fmaxf(ix, 0.f) * fmaxf(iy, 0.f);
        float denom = FA[k] + aj - inter;
        if (FP[k] < j && inter > 0.85f * denom && denom >= 0.f) {
            if (inter / denom > IOU_THRF) supp = true;
        }
    }
    float m = supp ? 0.f : 1.f;
    out[(size_t)n * 5 + 0] = b.x * m;
    out[(size_t)n * 5 + 1] = b.y * m;
    out[(size_t)n * 5 + 2] = b.z * m;
    out[(size_t)n * 5 + 3] = b.w * m;
    out[(size_t)n * 5 + 4] = scores[n] * m;
}

extern "C" void kernel_launch(void* const* d_in, const int* in_sizes, int n_in,
                              void* d_out, int out_size, void* d_ws, size_t ws_size,
                              hipStream_t stream) {
    const float* x      = (const float*)d_in[0];
    const float* anchors= (const float*)d_in[1];
    const float* dw_w   = (const float*)d_in[2];
    const float* pw_w   = (const float*)d_in[3];
    const float* bn1g   = (const float*)d_in[4];
    const float* bn1b   = (const float*)d_in[5];
    const float* bn1m   = (const float*)d_in[6];
    const float* bn1v   = (const float*)d_in[7];
    const float* anc_w  = (const float*)d_in[8];
    const float* ag     = (const float*)d_in[9];
    const float* ab     = (const float*)d_in[10];
    const float* am     = (const float*)d_in[11];
    const float* av     = (const float*)d_in[12];
    const float* obj_w  = (const float*)d_in[13];
    const float* og     = (const float*)d_in[14];
    const float* ob     = (const float*)d_in[15];
    const float* om     = (const float*)d_in[16];
    const float* ov     = (const float*)d_in[17];
    float* out = (float*)d_out;

    char* ws = (char*)d_ws;
    size_t off = 0;
    auto alloc = [&](size_t bytes) -> char* {
        char* p = ws + off;
        off = (off + bytes + 255) & ~(size_t)255;
        return p;
    };
    float* h0      = (float*)alloc(256 * 1024 * 4);
    float* h1      = (float*)alloc(256 * 1024 * 4);
    float* boxes   = (float*)alloc(NBOX * 4 * 4);
    float* scores  = (float*)alloc(NBOX * 4);
    unsigned* rank = (unsigned*)alloc(NBOX * 4);
    int* order     = (int*)alloc(NBOX * 4);
    float* sboxes  = (float*)alloc(NBOX * 4 * 4);
    float* sareas  = (float*)alloc(NBOX * 4);
    unsigned long long* rnz64 = (unsigned long long*)alloc(192 * 8);
    int* cidx      = (int*)alloc(CAND_CAP * 4);
    float4* cboxes = (float4*)alloc(CAND_CAP * 16);
    float* carea   = (float*)alloc(CAND_CAP * 4);
    int* knum      = (int*)alloc(256);
    int* fire_ord  = (int*)alloc(FIRE_CAP * 4);
    int* fire_cnt  = (int*)alloc(256);
    unsigned long long* gate  = (unsigned long long*)alloc((size_t)CAND_CAP * 64 * 8);
    unsigned long long* diag0 = (unsigned long long*)alloc(CAND_CAP * 8);
    unsigned long long* diag1 = (unsigned long long*)alloc(CAND_CAP * 8);

    hipMemsetAsync(rank, 0, NBOX * 4, stream);
    hipMemsetAsync(rnz64, 0, 192 * 8, stream);

    dw_conv<<<1024, 256, 0, stream>>>(x, dw_w, h0);
    pw_conv<<<dim3(4, 64), 256, 0, stream>>>(h0, pw_w, bn1g, bn1b, bn1m, bn1v, h1);
    heads<<<dim3(4, 45), 256, 0, stream>>>(h1, anc_w, ag, ab, am, av,
                                           obj_w, og, ob, om, ov, anchors, boxes, scores);
    rank_partial<<<dim3(36, 16), 256, 0, stream>>>(scores, rank);
    scatter_sorted<<<36, 256, 0, stream>>>(boxes, rank, order, sboxes, sareas);
    cand_detect<<<CD_TILES, 256, 0, stream>>>(sboxes, sareas, rnz64);
    compact_cand2<<<36, 256, 0, stream>>>(rnz64, sboxes, sareas, cidx, cboxes, carea, knum);
    gate_build<<<CAND_CAP / 4, 256, 0, stream>>>(cboxes, carea, knum, gate, diag0, diag1);
    nms_scan5<<<1, 512, 0, stream>>>(gate, diag0, diag1, knum, fire_ord, fire_cnt);
    finalize<<<36, 256, 0, stream>>>(boxes, scores, rank,
                                     cboxes, carea, cidx, fire_ord, fire_cnt, out);
}